// Round 3
// baseline (912.243 us; speedup 1.0000x reference)
//
#include <hip/hip_runtime.h>
#include <hip/hip_bf16.h>
#include <cstdint>

// ---------------- workspace layout (float offsets) ----------------
// a1 layout: [32 ic][9 q4][16384 samples] of float4  (conv1 out, relu'd)
#define N_A1   (16384ull*1152ull)
#define N_A2   (16384ull*256ull)
#define OFF_A1   0ull
#define OFF_A2   (OFF_A1 + N_A1)
#define OFF_W1T  (OFF_A2 + N_A2)           // fc1_w^T  [256][128]
#define OFF_W2T  (OFF_W1T + 32768ull)      // fc2_w^T  [135][64]
#define OFF_R1T  (OFF_W2T + 8640ull)
#define OFF_R2T  (OFF_R1T + 2048ull)
#define OFF_R3T  (OFF_R2T + 512ull)
#define OFF_C1T  (OFF_R3T + 160ull)
#define OFF_C2T  (OFF_C1T + 2048ull)
#define OFF_C3T  (OFF_C2T + 512ull)
#define OFF_H1T  (OFF_C3T + 160ull)
#define OFF_H2T  (OFF_H1T + 2048ull)
#define OFF_H3T  (OFF_H2T + 512ull)

// ---------------- prep: transpose all FC/head weights ----------------
__global__ __launch_bounds__(256) void k_prep(
    const float* __restrict__ f1w, const float* __restrict__ f2w,
    const float* __restrict__ r1, const float* __restrict__ r2, const float* __restrict__ r3,
    const float* __restrict__ c1, const float* __restrict__ c2, const float* __restrict__ c3,
    const float* __restrict__ h1, const float* __restrict__ h2, const float* __restrict__ h3,
    float* __restrict__ ws) {
  const float* srcs[11] = {f1w, f2w, r1, r2, r3, c1, c2, c3, h1, h2, h3};
  float* dsts[11] = {ws+OFF_W1T, ws+OFF_W2T, ws+OFF_R1T, ws+OFF_R2T, ws+OFF_R3T,
                     ws+OFF_C1T, ws+OFF_C2T, ws+OFF_C3T, ws+OFF_H1T, ws+OFF_H2T, ws+OFF_H3T};
  const int Rs[11] = {128, 64, 32, 16, 10, 32, 16, 10, 32, 16, 7};
  const int Cs[11] = {256, 135, 64, 32, 16, 64, 32, 16, 64, 32, 16};
  for (int seg = 0; seg < 11; ++seg) {
    int n = Rs[seg] * Cs[seg];
    for (int i = blockIdx.x * blockDim.x + threadIdx.x; i < n; i += gridDim.x * blockDim.x) {
      int r = i / Cs[seg];
      int c = i - r * Cs[seg];
      dsts[seg][c * Rs[seg] + r] = srcs[seg][i];
    }
  }
}

// ---------------- conv1: [B,9,10,10] -> relu -> a1[ic(oc)][q4][s]f4 ----------------
// block = 512 thr = 8 waves; wave = 32 samples x 2 oc; block covers 16 oc.
// 2 blocks per 32-sample tile (ocbase 0/16). Weights via s_load (wave-uniform).
// launch_bounds(512,1): 512-VGPR budget — needs ~165 VGPR, MUST NOT cap at 128 (spills).
__global__ __launch_bounds__(512, 1) void k_conv1(
    const float* __restrict__ board, const float* __restrict__ w,
    const float* __restrict__ bias_g, float* __restrict__ a1) {
  __shared__ float buf[2][32 * 100];          // one ic-plane, 32 samples, dbuf
  const int tid  = threadIdx.x;
  const int lane = tid & 63;
  const int s    = lane & 31;                 // sample within tile
  const int oh   = lane >> 5;                 // which oc of the pair
  const int wv   = __builtin_amdgcn_readfirstlane(tid >> 6);   // wave id 0..7
  const int tile = blockIdx.x >> 1;
  const int ocb  = (blockIdx.x & 1) * 16;     // block oc base
  const int ocp  = ocb + wv * 2;              // wave's oc pair base (uniform)
  const int s0   = tile * 32;

  const float4* g4 = reinterpret_cast<const float4*>(board);
  const int i0 = tid;                 // < 512
  const int i1 = 512 + tid;           // valid if tid < 288
  const int s_0 = i0 / 25, q_0 = i0 - s_0 * 25;
  const int s_1 = i1 / 25, q_1 = i1 - s_1 * 25;

  float4 pf0, pf1;
  pf0 = g4[(size_t)(s0 + s_0) * 225 + q_0];
  if (tid < 288) pf1 = g4[(size_t)(s0 + s_1) * 225 + q_1];
  *reinterpret_cast<float4*>(&buf[0][s_0 * 100 + q_0 * 4]) = pf0;
  if (tid < 288) *reinterpret_cast<float4*>(&buf[0][s_1 * 100 + q_1 * 4]) = pf1;
  __syncthreads();

  float acc[36];
  {
    float bv = bias_g[ocp + oh];
#pragma unroll
    for (int p = 0; p < 36; ++p) acc[p] = bv;
  }

#pragma unroll 1
  for (int ic = 0; ic < 9; ++ic) {
    const int cur = ic & 1;
    if (ic < 8) {
      pf0 = g4[(size_t)(s0 + s_0) * 225 + (ic + 1) * 25 + q_0];
      if (tid < 288) pf1 = g4[(size_t)(s0 + s_1) * 225 + (ic + 1) * 25 + q_1];
    }
    float plane[100];
    {
      const float4* p4 = reinterpret_cast<const float4*>(&buf[cur][s * 100]);
#pragma unroll
      for (int q = 0; q < 25; ++q) {
        float4 v = p4[q];
        plane[4*q] = v.x; plane[4*q+1] = v.y; plane[4*q+2] = v.z; plane[4*q+3] = v.w;
      }
    }
    const float* wbase = w + (size_t)ocp * 225 + ic * 25;   // uniform -> s_load
#pragma unroll
    for (int ky = 0; ky < 5; ++ky) {
#pragma unroll
      for (int kx = 0; kx < 5; ++kx) {
        const float wa = wbase[ky * 5 + kx];
        const float wb = wbase[225 + ky * 5 + kx];
        const float wvv = oh ? wb : wa;
#pragma unroll
        for (int r = 0; r < 6; ++r) {
#pragma unroll
          for (int c = 0; c < 6; ++c) {
            acc[r * 6 + c] = fmaf(wvv, plane[(r + ky) * 10 + c + kx], acc[r * 6 + c]);
          }
        }
      }
    }
    if (ic < 8) {
      *reinterpret_cast<float4*>(&buf[cur ^ 1][s_0 * 100 + q_0 * 4]) = pf0;
      if (tid < 288) *reinterpret_cast<float4*>(&buf[cur ^ 1][s_1 * 100 + q_1 * 4]) = pf1;
      __syncthreads();
    }
  }

  const int oc = ocp + oh;
  float4* o4 = reinterpret_cast<float4*>(a1);
#pragma unroll
  for (int q = 0; q < 9; ++q) {
    float4 v;
    v.x = fmaxf(acc[4*q],   0.f); v.y = fmaxf(acc[4*q+1], 0.f);
    v.z = fmaxf(acc[4*q+2], 0.f); v.w = fmaxf(acc[4*q+3], 0.f);
    o4[(size_t)(oc * 9 + q) * 16384ull + s0 + s] = v;
  }
}

// -------- conv2 + relu + 2x2 maxpool: a1 -> a2[s][256] --------
// block = 512 thr = 8 waves; lane = sample (64/tile); wave owns 8 oc.
// launch_bounds(512,1): needs ~205 VGPR (acc 128 + plane 36 + pf 20 + addr).
__global__ __launch_bounds__(512, 1) void k_conv2(
    const float* __restrict__ a1, const float* __restrict__ w,
    const float* __restrict__ bias_g, float* __restrict__ a2) {
  __shared__ float buf[2][64 * 148];          // 4-ic chunk, pitch 148, dbuf (75776 B)
  const int tid = threadIdx.x;
  const int s   = tid & 63;
  const int wv  = __builtin_amdgcn_readfirstlane(tid >> 6);
  const int ocb = wv * 8;
  const int s0  = blockIdx.x * 64;

  const float4* g4 = reinterpret_cast<const float4*>(a1);
  float4 pf[5];

#define C2_LOAD(c_)                                                          \
  _Pragma("unroll")                                                          \
  for (int r = 0; r < 5; ++r) {                                              \
    int i = tid + 512 * r;                                                   \
    if (r < 4 || tid < 256) {                                                \
      int icl = i / 576; int rem = i - icl * 576;                            \
      int q4 = rem >> 6; int sl = rem & 63;                                  \
      pf[r] = g4[(size_t)(((c_) * 4 + icl) * 9 + q4) * 16384ull + s0 + sl];  \
    }                                                                        \
  }
#define C2_WRITE(b_)                                                         \
  _Pragma("unroll")                                                          \
  for (int r = 0; r < 5; ++r) {                                              \
    int i = tid + 512 * r;                                                   \
    if (r < 4 || tid < 256) {                                                \
      int icl = i / 576; int rem = i - icl * 576;                            \
      int q4 = rem >> 6; int sl = rem & 63;                                  \
      *reinterpret_cast<float4*>(&buf[b_][sl * 148 + icl * 36 + q4 * 4]) = pf[r]; \
    }                                                                        \
  }

  C2_LOAD(0); C2_WRITE(0); __syncthreads();

  float acc[8][16];
#pragma unroll
  for (int j = 0; j < 8; ++j) {
    float bv = bias_g[ocb + j];
#pragma unroll
    for (int p = 0; p < 16; ++p) acc[j][p] = bv;
  }

#pragma unroll 1
  for (int c = 0; c < 8; ++c) {
    const int cur = c & 1;
    if (c < 7) { C2_LOAD(c + 1); }
#pragma unroll
    for (int icl = 0; icl < 4; ++icl) {
      float plane[36];
      {
        const float4* p4 = reinterpret_cast<const float4*>(&buf[cur][s * 148 + icl * 36]);
#pragma unroll
        for (int q = 0; q < 9; ++q) {
          float4 v = p4[q];
          plane[4*q] = v.x; plane[4*q+1] = v.y; plane[4*q+2] = v.z; plane[4*q+3] = v.w;
        }
      }
      const int ic = c * 4 + icl;
#pragma unroll
      for (int j = 0; j < 8; ++j) {
        const float* wr = w + (size_t)(ocb + j) * 288 + ic * 9;   // uniform -> s_load
#pragma unroll
        for (int ky = 0; ky < 3; ++ky) {
#pragma unroll
          for (int kx = 0; kx < 3; ++kx) {
            const float wvv = wr[ky * 3 + kx];
#pragma unroll
            for (int y = 0; y < 4; ++y) {
#pragma unroll
              for (int x = 0; x < 4; ++x) {
                acc[j][y*4+x] = fmaf(wvv, plane[(y+ky)*6 + x + kx], acc[j][y*4+x]);
              }
            }
          }
        }
      }
    }
    if (c < 7) { C2_WRITE(cur ^ 1); }
    __syncthreads();
  }

  // pool + relu -> LDS transpose (pitch 260) -> coalesced a2 rows
  float* trans = &buf[0][0];
#pragma unroll
  for (int j = 0; j < 8; ++j) {
    float4 v;
    v.x = fmaxf(fmaxf(acc[j][0],  acc[j][1]),  fmaxf(acc[j][4],  acc[j][5]));
    v.y = fmaxf(fmaxf(acc[j][2],  acc[j][3]),  fmaxf(acc[j][6],  acc[j][7]));
    v.z = fmaxf(fmaxf(acc[j][8],  acc[j][9]),  fmaxf(acc[j][12], acc[j][13]));
    v.w = fmaxf(fmaxf(acc[j][10], acc[j][11]), fmaxf(acc[j][14], acc[j][15]));
    v.x = fmaxf(v.x, 0.f); v.y = fmaxf(v.y, 0.f); v.z = fmaxf(v.z, 0.f); v.w = fmaxf(v.w, 0.f);
    *reinterpret_cast<float4*>(&trans[s * 260 + (ocb + j) * 4]) = v;
  }
  __syncthreads();
  float4* o4 = reinterpret_cast<float4*>(a2);
#pragma unroll
  for (int r = 0; r < 8; ++r) {
    int jj = tid + 512 * r;
    int sl = jj >> 6, k4 = jj & 63;
    o4[(size_t)(s0 + sl) * 64ull + k4] = *reinterpret_cast<const float4*>(&trans[sl * 260 + k4 * 4]);
  }
#undef C2_LOAD
#undef C2_WRITE
}

// -------- fc1 -> concat -> fc2 -> 3 heads -> outer product --------
__global__ __launch_bounds__(256) void k_fc(
    const float* __restrict__ a2, const float* __restrict__ card,
    const float* __restrict__ ws,
    const float* __restrict__ f1b, const float* __restrict__ f2b,
    const float* __restrict__ rb1, const float* __restrict__ rb2, const float* __restrict__ rb3,
    const float* __restrict__ cb1, const float* __restrict__ cb2, const float* __restrict__ cb3,
    const float* __restrict__ hb1g, const float* __restrict__ hb2g, const float* __restrict__ hb3g,
    float* __restrict__ out) {
  __shared__ float xb[64 * 257];
  __shared__ float cbuf[64 * 8];
  __shared__ float h1s[64 * 129];
  __shared__ float h2s[64 * 65];
  __shared__ float ro[64 * 12];
  __shared__ float co[64 * 12];
  __shared__ float ha[64 * 8];
  const int tid = threadIdx.x;
  const int s0 = blockIdx.x * 64;

  for (int i = tid; i < 64 * 256; i += 256) {
    int s_ = i >> 8, k_ = i & 255;
    xb[s_ * 257 + k_] = a2[(size_t)(s0 + s_) * 256ull + k_];
  }
  for (int i = tid; i < 64 * 7; i += 256) {
    int s_ = i / 7, k_ = i - s_ * 7;
    cbuf[s_ * 8 + k_] = card[(size_t)(s0 + s_) * 7ull + k_];
  }
  __syncthreads();

  const int s = tid & 63;
  const int grp = __builtin_amdgcn_readfirstlane(tid >> 6);
  const float* w1t = ws + OFF_W1T;
  const float* w2t = ws + OFF_W2T;

  {
    const int j0 = grp * 32;
    float acc[32];
#pragma unroll
    for (int j = 0; j < 32; ++j) acc[j] = f1b[j0 + j];
    for (int k = 0; k < 256; ++k) {
      float xk = xb[s * 257 + k];
      const float* wr = w1t + k * 128 + j0;
#pragma unroll
      for (int j = 0; j < 32; ++j) acc[j] = fmaf(xk, wr[j], acc[j]);
    }
#pragma unroll
    for (int j = 0; j < 32; ++j) h1s[s * 129 + j0 + j] = fmaxf(acc[j], 0.f);
  }
  __syncthreads();

  {
    const int m0 = grp * 16;
    float acc[16];
#pragma unroll
    for (int m = 0; m < 16; ++m) acc[m] = f2b[m0 + m];
    for (int k = 0; k < 128; ++k) {
      float hk = h1s[s * 129 + k];
      const float* wr = w2t + k * 64 + m0;
#pragma unroll
      for (int m = 0; m < 16; ++m) acc[m] = fmaf(hk, wr[m], acc[m]);
    }
#pragma unroll
    for (int k = 0; k < 7; ++k) {
      float hk = cbuf[s * 8 + k];
      const float* wr = w2t + (128 + k) * 64 + m0;
#pragma unroll
      for (int m = 0; m < 16; ++m) acc[m] = fmaf(hk, wr[m], acc[m]);
    }
#pragma unroll
    for (int m = 0; m < 16; ++m) h2s[s * 65 + m0 + m] = fmaxf(acc[m], 0.f);
  }
  __syncthreads();

  if (grp < 3) {
    const float* hw1 = (grp == 0) ? ws + OFF_R1T : (grp == 1) ? ws + OFF_C1T : ws + OFF_H1T;
    const float* hw2 = (grp == 0) ? ws + OFF_R2T : (grp == 1) ? ws + OFF_C2T : ws + OFF_H2T;
    const float* hw3 = (grp == 0) ? ws + OFF_R3T : (grp == 1) ? ws + OFF_C3T : ws + OFF_H3T;
    const float* b1 = (grp == 0) ? rb1 : (grp == 1) ? cb1 : hb1g;
    const float* b2 = (grp == 0) ? rb2 : (grp == 1) ? cb2 : hb2g;
    const float* b3 = (grp == 0) ? rb3 : (grp == 1) ? cb3 : hb3g;

    float g1[32];
#pragma unroll
    for (int j = 0; j < 32; ++j) g1[j] = b1[j];
    for (int k = 0; k < 64; ++k) {
      float hk = h2s[s * 65 + k];
      const float* wr = hw1 + k * 32;
#pragma unroll
      for (int j = 0; j < 32; ++j) g1[j] = fmaf(hk, wr[j], g1[j]);
    }
    float g2[16];
#pragma unroll
    for (int m = 0; m < 16; ++m) g2[m] = b2[m];
#pragma unroll
    for (int k = 0; k < 32; ++k) {
      const float* wr = hw2 + k * 16;
#pragma unroll
      for (int m = 0; m < 16; ++m) g2[m] = fmaf(g1[k], wr[m], g2[m]);
    }
    if (grp == 2) {
      float g3[7];
#pragma unroll
      for (int m = 0; m < 7; ++m) g3[m] = b3[m];
#pragma unroll
      for (int k = 0; k < 16; ++k) {
        const float* wr = hw3 + k * 7;
#pragma unroll
        for (int m = 0; m < 7; ++m) g3[m] = fmaf(g2[k], wr[m], g3[m]);
      }
#pragma unroll
      for (int m = 0; m < 7; ++m) ha[s * 8 + m] = g3[m];
    } else {
      float g3[10];
#pragma unroll
      for (int m = 0; m < 10; ++m) g3[m] = b3[m];
#pragma unroll
      for (int k = 0; k < 16; ++k) {
        const float* wr = hw3 + k * 10;
#pragma unroll
        for (int m = 0; m < 10; ++m) g3[m] = fmaf(g2[k], wr[m], g3[m]);
      }
      float* dst = (grp == 0) ? ro : co;
#pragma unroll
      for (int m = 0; m < 10; ++m) dst[s * 12 + m] = g3[m];
    }
  }
  __syncthreads();

  for (int idx = tid; idx < 64 * 700; idx += 256) {
    int s_ = idx / 700;
    int q = idx - s_ * 700;
    int h = q / 100;
    int rm = q - h * 100;
    int r = rm / 10;
    int c = rm - r * 10;
    out[(size_t)(s0 + s_) * 700ull + q] = ha[s_ * 8 + h] * ro[s_ * 12 + r] * co[s_ * 12 + c];
  }
}

extern "C" void kernel_launch(void* const* d_in, const int* in_sizes, int n_in,
                              void* d_out, int out_size, void* d_ws, size_t ws_size,
                              hipStream_t stream) {
  const float* board = (const float*)d_in[0];
  const float* card  = (const float*)d_in[1];
  const float* c1w = (const float*)d_in[2];
  const float* c1b = (const float*)d_in[3];
  const float* c2w = (const float*)d_in[4];
  const float* c2b = (const float*)d_in[5];
  const float* f1w = (const float*)d_in[6];
  const float* f1b = (const float*)d_in[7];
  const float* f2w = (const float*)d_in[8];
  const float* f2b = (const float*)d_in[9];
  const float* r1w = (const float*)d_in[10];
  const float* r1b = (const float*)d_in[11];
  const float* r2w = (const float*)d_in[12];
  const float* r2b = (const float*)d_in[13];
  const float* r3w = (const float*)d_in[14];
  const float* r3b = (const float*)d_in[15];
  const float* co1w = (const float*)d_in[16];
  const float* co1b = (const float*)d_in[17];
  const float* co2w = (const float*)d_in[18];
  const float* co2b = (const float*)d_in[19];
  const float* co3w = (const float*)d_in[20];
  const float* co3b = (const float*)d_in[21];
  const float* h1w = (const float*)d_in[22];
  const float* h1b = (const float*)d_in[23];
  const float* h2w = (const float*)d_in[24];
  const float* h2b = (const float*)d_in[25];
  const float* h3w = (const float*)d_in[26];
  const float* h3b = (const float*)d_in[27];

  float* ws = (float*)d_ws;
  float* out = (float*)d_out;
  float* a1 = ws + OFF_A1;
  float* a2 = ws + OFF_A2;

  k_prep<<<32, 256, 0, stream>>>(f1w, f2w, r1w, r2w, r3w, co1w, co2w, co3w, h1w, h2w, h3w, ws);
  k_conv1<<<1024, 512, 0, stream>>>(board, c1w, c1b, a1);
  k_conv2<<<256, 512, 0, stream>>>(a1, c2w, c2b, a2);
  k_fc<<<256, 256, 0, stream>>>(a2, card, ws, f1b, f2b,
                                r1b, r2b, r3b, co1b, co2b, co3b, h1b, h2b, h3b, out);
}

// Round 4
// 433.427 us; speedup vs baseline: 2.1047x; 2.1047x over previous
//
#include <hip/hip_runtime.h>
#include <hip/hip_bf16.h>
#include <cstdint>

// ---------------- workspace layout (float offsets) ----------------
// a1 layout: [32 ic][9 q4][16384 s] of float4   (conv1 out, relu'd)
// a2 layout: [64 oc][16384 s] of float4         (pooled, transposed)
#define N_A1   (16384ull*1152ull)
#define N_A2   (16384ull*256ull)
#define OFF_A1   0ull
#define OFF_A2   (OFF_A1 + N_A1)
#define OFF_W1T  (OFF_A2 + N_A2)           // fc1_w^T  [256][128]
#define OFF_W2T  (OFF_W1T + 32768ull)      // fc2_w^T  [135][64]
#define OFF_R1T  (OFF_W2T + 8640ull)
#define OFF_R2T  (OFF_R1T + 2048ull)
#define OFF_R3T  (OFF_R2T + 512ull)
#define OFF_C1T  (OFF_R3T + 160ull)
#define OFF_C2T  (OFF_C1T + 2048ull)
#define OFF_C3T  (OFF_C2T + 512ull)
#define OFF_H1T  (OFF_C3T + 160ull)
#define OFF_H2T  (OFF_H1T + 2048ull)
#define OFF_H3T  (OFF_H2T + 512ull)

typedef __attribute__((address_space(1))) const unsigned int GU32;
typedef __attribute__((address_space(3))) unsigned int LU32;
__device__ __forceinline__ void gl_lds16(const void* g, void* l) {
  // async global->LDS, 16B/lane; LDS dest = wave-uniform base + lane*16
  __builtin_amdgcn_global_load_lds((GU32*)g, (LU32*)l, 16, 0, 0);
}

// ---------------- prep: transpose all FC/head weights ----------------
__global__ __launch_bounds__(256) void k_prep(
    const float* __restrict__ f1w, const float* __restrict__ f2w,
    const float* __restrict__ r1, const float* __restrict__ r2, const float* __restrict__ r3,
    const float* __restrict__ c1, const float* __restrict__ c2, const float* __restrict__ c3,
    const float* __restrict__ h1, const float* __restrict__ h2, const float* __restrict__ h3,
    float* __restrict__ ws) {
  const float* srcs[11] = {f1w, f2w, r1, r2, r3, c1, c2, c3, h1, h2, h3};
  float* dsts[11] = {ws+OFF_W1T, ws+OFF_W2T, ws+OFF_R1T, ws+OFF_R2T, ws+OFF_R3T,
                     ws+OFF_C1T, ws+OFF_C2T, ws+OFF_C3T, ws+OFF_H1T, ws+OFF_H2T, ws+OFF_H3T};
  const int Rs[11] = {128, 64, 32, 16, 10, 32, 16, 10, 32, 16, 7};
  const int Cs[11] = {256, 135, 64, 32, 16, 64, 32, 16, 64, 32, 16};
  for (int seg = 0; seg < 11; ++seg) {
    int n = Rs[seg] * Cs[seg];
    for (int i = blockIdx.x * blockDim.x + threadIdx.x; i < n; i += gridDim.x * blockDim.x) {
      int r = i / Cs[seg];
      int c = i - r * Cs[seg];
      dsts[seg][c * Rs[seg] + r] = srcs[seg][i];
    }
  }
}

// ---------------- conv1: board[B,9,10,10] -> relu -> a1[oc][q4][s] ----------------
// 512 thr = 8 waves; lane = sample (64/tile); wave = 1 oc; block = 8 oc.
// grid = 256 tiles * 4 ocb = 1024.  ~110 VGPR/thread (no spill by design).
__global__ __launch_bounds__(512) void k_conv1(
    const float* __restrict__ board, const float* __restrict__ w,
    const float* __restrict__ bias_g, float* __restrict__ a1) {
  __shared__ float4 buf[2][1600];             // [q 25][s 64] per ic, dbuf, 51.2 KB
  const int tid = threadIdx.x;
  const int s   = tid & 63;
  const int wv  = __builtin_amdgcn_readfirstlane(tid >> 6);    // 0..7
  const int tile = blockIdx.x >> 2;
  const int ocb  = (blockIdx.x & 3) * 8;
  const int oc   = ocb + wv;                  // wave-uniform
  const int s0   = tile * 64;

  const float4* bd4 = reinterpret_cast<const float4*>(board);

  // stage ic=0: 25 slices of 64 f4; slice sg: global f4 = (s0+lane)*225 + ic*25 + sg
#define C1_STAGE(ic_, b_)                                                     \
  {                                                                           \
    _Pragma("unroll")                                                         \
    for (int r = 0; r < 3; ++r) {                                             \
      int sg = wv + 8 * r;                                                    \
      gl_lds16(&bd4[(size_t)(s0 + s) * 225 + (ic_) * 25 + sg],               \
               &buf[b_][sg * 64]);                                            \
    }                                                                         \
    if (wv == 0)                                                              \
      gl_lds16(&bd4[(size_t)(s0 + s) * 225 + (ic_) * 25 + 24],               \
               &buf[b_][24 * 64]);                                            \
  }

  C1_STAGE(0, 0);
  __syncthreads();

  float acc[36];
  {
    float bv = bias_g[oc];
#pragma unroll
    for (int p = 0; p < 36; ++p) acc[p] = bv;
  }

  float4 wnd[15];
#pragma unroll 1
  for (int ic = 0; ic < 9; ++ic) {
    const int cur = ic & 1;
    if (ic < 8) C1_STAGE(ic + 1, cur ^ 1);

    const float* wbase = w + (size_t)oc * 225 + ic * 25;   // uniform -> s_load
    // output rows in pairs p: rows {2p,2p+1} need sample dwords [20p, 20p+60)
#pragma unroll
    for (int p = 0; p < 3; ++p) {
      if (p == 0) {
#pragma unroll
        for (int q = 0; q < 15; ++q) wnd[q] = buf[cur][q * 64 + s];
      } else {
#pragma unroll
        for (int t = 0; t < 5; ++t) {
          const int q = 5 * p + 10 + t;
          wnd[q % 15] = buf[cur][q * 64 + s];
        }
      }
#pragma unroll
      for (int ky = 0; ky < 5; ++ky) {
#pragma unroll
        for (int kx = 0; kx < 5; ++kx) {
          const float wt = wbase[ky * 5 + kx];
#pragma unroll
          for (int Rl = 0; Rl < 2; ++Rl) {
#pragma unroll
            for (int c2 = 0; c2 < 6; ++c2) {
              const int g = (Rl + ky) * 10 + (c2 + kx) + 20 * p;  // compile-time
              const float xv = (&wnd[(g >> 2) % 15].x)[g & 3];
              acc[(2 * p + Rl) * 6 + c2] = fmaf(wt, xv, acc[(2 * p + Rl) * 6 + c2]);
            }
          }
        }
      }
    }
    __syncthreads();
  }

  float4* o4 = reinterpret_cast<float4*>(a1);
#pragma unroll
  for (int q = 0; q < 9; ++q) {
    float4 v;
    v.x = fmaxf(acc[4*q],   0.f); v.y = fmaxf(acc[4*q+1], 0.f);
    v.z = fmaxf(acc[4*q+2], 0.f); v.w = fmaxf(acc[4*q+3], 0.f);
    o4[(size_t)(oc * 9 + q) * 16384ull + s0 + s] = v;
  }
#undef C1_STAGE
}

// -------- conv2 + relu + 2x2 maxpool: a1 -> a2T[oc][s] --------
// 512 thr = 8 waves; lane = sample (64/tile); wave = 4 oc; block = 32 oc.
// grid = 256 tiles * 2 ocb = 512.  ~115 VGPR/thread.
__global__ __launch_bounds__(512) void k_conv2(
    const float* __restrict__ a1, const float* __restrict__ w,
    const float* __restrict__ bias_g, float* __restrict__ a2t) {
  __shared__ float4 buf[2][2304];             // [icl 4][q4 9][s 64] per chunk, 73.7 KB
  const int tid = threadIdx.x;
  const int s   = tid & 63;
  const int wv  = __builtin_amdgcn_readfirstlane(tid >> 6);
  const int ocb = (blockIdx.x & 1) * 32 + wv * 4;   // wave's 4-oc base (uniform)
  const int s0  = (blockIdx.x >> 1) * 64;

  const float4* a14 = reinterpret_cast<const float4*>(a1);

  // chunk c: 36 slices; slice sg: global f4 = (c*36+sg)*16384 + s0 + lane
#define C2_STAGE(c_, b_)                                                      \
  {                                                                           \
    _Pragma("unroll")                                                         \
    for (int r = 0; r < 4; ++r) {                                             \
      int sg = wv + 8 * r;                                                    \
      gl_lds16(&a14[(size_t)((c_) * 36 + sg) * 16384ull + s0 + s],           \
               &buf[b_][sg * 64]);                                            \
    }                                                                         \
    if (wv < 4)                                                               \
      gl_lds16(&a14[(size_t)((c_) * 36 + 32 + wv) * 16384ull + s0 + s],      \
               &buf[b_][(32 + wv) * 64]);                                     \
  }

  C2_STAGE(0, 0);
  __syncthreads();

  float acc[4][16];
#pragma unroll
  for (int j = 0; j < 4; ++j) {
    float bv = bias_g[ocb + j];
#pragma unroll
    for (int p = 0; p < 16; ++p) acc[j][p] = bv;
  }

#pragma unroll 1
  for (int c = 0; c < 8; ++c) {
    const int cur = c & 1;
    if (c < 7) C2_STAGE(c + 1, cur ^ 1);

    for (int icl = 0; icl < 4; ++icl) {
      float plane[36];
#pragma unroll
      for (int q4 = 0; q4 < 9; ++q4) {
        float4 v = buf[cur][(icl * 9 + q4) * 64 + s];
        plane[q4*4] = v.x; plane[q4*4+1] = v.y; plane[q4*4+2] = v.z; plane[q4*4+3] = v.w;
      }
      const int ic = c * 4 + icl;
#pragma unroll
      for (int j = 0; j < 4; ++j) {
        const float* wr = w + (size_t)(ocb + j) * 288 + ic * 9;   // uniform -> s_load
#pragma unroll
        for (int ky = 0; ky < 3; ++ky) {
#pragma unroll
          for (int kx = 0; kx < 3; ++kx) {
            const float wt = wr[ky * 3 + kx];
#pragma unroll
            for (int y = 0; y < 4; ++y) {
#pragma unroll
              for (int x = 0; x < 4; ++x) {
                acc[j][y*4+x] = fmaf(wt, plane[(y+ky)*6 + x + kx], acc[j][y*4+x]);
              }
            }
          }
        }
      }
    }
    __syncthreads();
  }

  // pool + relu -> a2T[oc][s]: coalesced f4 store per oc
  float4* o4 = reinterpret_cast<float4*>(a2t);
#pragma unroll
  for (int j = 0; j < 4; ++j) {
    float4 v;
    v.x = fmaxf(fmaxf(acc[j][0],  acc[j][1]),  fmaxf(acc[j][4],  acc[j][5]));
    v.y = fmaxf(fmaxf(acc[j][2],  acc[j][3]),  fmaxf(acc[j][6],  acc[j][7]));
    v.z = fmaxf(fmaxf(acc[j][8],  acc[j][9]),  fmaxf(acc[j][12], acc[j][13]));
    v.w = fmaxf(fmaxf(acc[j][10], acc[j][11]), fmaxf(acc[j][14], acc[j][15]));
    v.x = fmaxf(v.x, 0.f); v.y = fmaxf(v.y, 0.f); v.z = fmaxf(v.z, 0.f); v.w = fmaxf(v.w, 0.f);
    o4[(size_t)(ocb + j) * 16384ull + s0 + s] = v;
  }
#undef C2_STAGE
}

// -------- fc1 -> concat -> fc2 -> 3 heads -> outer product --------
// 512 thr = 8 waves; lane = sample (64/block); grid 256.
__global__ __launch_bounds__(512) void k_fc(
    const float* __restrict__ a2t, const float* __restrict__ card,
    const float* __restrict__ ws,
    const float* __restrict__ f1b, const float* __restrict__ f2b,
    const float* __restrict__ rb1, const float* __restrict__ rb2, const float* __restrict__ rb3,
    const float* __restrict__ cb1, const float* __restrict__ cb2, const float* __restrict__ cb3,
    const float* __restrict__ hb1g, const float* __restrict__ hb2g, const float* __restrict__ hb3g,
    float* __restrict__ out) {
  __shared__ float xb[64 * 257];     // (257%32==1 -> conflict-free column reads)
  __shared__ float cbuf[64 * 8];
  __shared__ float h1s[64 * 129];
  __shared__ float h2s[64 * 65];
  __shared__ float ro[64 * 12];
  __shared__ float co[64 * 12];
  __shared__ float ha[64 * 8];
  const int tid = threadIdx.x;
  const int s0 = blockIdx.x * 64;
  const float4* x4 = reinterpret_cast<const float4*>(a2t);

  for (int i = tid; i < 4096; i += 512) {     // x: [s][256] from a2T[k4][s]
    int k4 = i >> 6, s_ = i & 63;
    float4 v = x4[(size_t)k4 * 16384ull + s0 + s_];
    float* dst = &xb[s_ * 257 + k4 * 4];
    dst[0] = v.x; dst[1] = v.y; dst[2] = v.z; dst[3] = v.w;
  }
  if (tid < 448) {
    int s_ = tid / 7, k_ = tid - s_ * 7;
    cbuf[s_ * 8 + k_] = card[(size_t)(s0 + s_) * 7ull + k_];
  }
  __syncthreads();

  const int s = tid & 63;
  const int grp = __builtin_amdgcn_readfirstlane(tid >> 6);   // 0..7
  const float* w1t = ws + OFF_W1T;
  const float* w2t = ws + OFF_W2T;

  // ---- fc1: 256 -> 128, relu (8 waves x 16 outputs) ----
  {
    const int j0 = grp * 16;
    float acc[16];
#pragma unroll
    for (int j = 0; j < 16; ++j) acc[j] = f1b[j0 + j];
    for (int k = 0; k < 256; ++k) {
      float xk = xb[s * 257 + k];
      const float* wr = w1t + k * 128 + j0;
#pragma unroll
      for (int j = 0; j < 16; ++j) acc[j] = fmaf(xk, wr[j], acc[j]);
    }
#pragma unroll
    for (int j = 0; j < 16; ++j) h1s[s * 129 + j0 + j] = fmaxf(acc[j], 0.f);
  }
  __syncthreads();

  // ---- fc2: 135 -> 64, relu (8 waves x 8 outputs) ----
  {
    const int m0 = grp * 8;
    float acc[8];
#pragma unroll
    for (int m = 0; m < 8; ++m) acc[m] = f2b[m0 + m];
    for (int k = 0; k < 128; ++k) {
      float hk = h1s[s * 129 + k];
      const float* wr = w2t + k * 64 + m0;
#pragma unroll
      for (int m = 0; m < 8; ++m) acc[m] = fmaf(hk, wr[m], acc[m]);
    }
#pragma unroll
    for (int k = 0; k < 7; ++k) {
      float hk = cbuf[s * 8 + k];
      const float* wr = w2t + (128 + k) * 64 + m0;
#pragma unroll
      for (int m = 0; m < 8; ++m) acc[m] = fmaf(hk, wr[m], acc[m]);
    }
#pragma unroll
    for (int m = 0; m < 8; ++m) h2s[s * 65 + m0 + m] = fmaxf(acc[m], 0.f);
  }
  __syncthreads();

  // ---- heads (wave 0: row, 1: col, 2: hand; waves 3-7 idle) ----
  if (grp < 3) {
    const float* hw1 = (grp == 0) ? ws + OFF_R1T : (grp == 1) ? ws + OFF_C1T : ws + OFF_H1T;
    const float* hw2 = (grp == 0) ? ws + OFF_R2T : (grp == 1) ? ws + OFF_C2T : ws + OFF_H2T;
    const float* hw3 = (grp == 0) ? ws + OFF_R3T : (grp == 1) ? ws + OFF_C3T : ws + OFF_H3T;
    const float* b1 = (grp == 0) ? rb1 : (grp == 1) ? cb1 : hb1g;
    const float* b2 = (grp == 0) ? rb2 : (grp == 1) ? cb2 : hb2g;
    const float* b3 = (grp == 0) ? rb3 : (grp == 1) ? cb3 : hb3g;

    float g1[32];
#pragma unroll
    for (int j = 0; j < 32; ++j) g1[j] = b1[j];
    for (int k = 0; k < 64; ++k) {
      float hk = h2s[s * 65 + k];
      const float* wr = hw1 + k * 32;
#pragma unroll
      for (int j = 0; j < 32; ++j) g1[j] = fmaf(hk, wr[j], g1[j]);
    }
    float g2[16];
#pragma unroll
    for (int m = 0; m < 16; ++m) g2[m] = b2[m];
#pragma unroll
    for (int k = 0; k < 32; ++k) {
      const float* wr = hw2 + k * 16;
#pragma unroll
      for (int m = 0; m < 16; ++m) g2[m] = fmaf(g1[k], wr[m], g2[m]);
    }
    if (grp == 2) {
      float g3[7];
#pragma unroll
      for (int m = 0; m < 7; ++m) g3[m] = b3[m];
#pragma unroll
      for (int k = 0; k < 16; ++k) {
        const float* wr = hw3 + k * 7;
#pragma unroll
        for (int m = 0; m < 7; ++m) g3[m] = fmaf(g2[k], wr[m], g3[m]);
      }
#pragma unroll
      for (int m = 0; m < 7; ++m) ha[s * 8 + m] = g3[m];
    } else {
      float g3[10];
#pragma unroll
      for (int m = 0; m < 10; ++m) g3[m] = b3[m];
#pragma unroll
      for (int k = 0; k < 16; ++k) {
        const float* wr = hw3 + k * 10;
#pragma unroll
        for (int m = 0; m < 10; ++m) g3[m] = fmaf(g2[k], wr[m], g3[m]);
      }
      float* dst = (grp == 0) ? ro : co;
#pragma unroll
      for (int m = 0; m < 10; ++m) dst[s * 12 + m] = g3[m];
    }
  }
  __syncthreads();

  // ---- outer product ----
  for (int idx = tid; idx < 64 * 700; idx += 512) {
    int s_ = idx / 700;
    int q = idx - s_ * 700;
    int h = q / 100;
    int rm = q - h * 100;
    int r = rm / 10;
    int c = rm - r * 10;
    out[(size_t)(s0 + s_) * 700ull + q] = ha[s_ * 8 + h] * ro[s_ * 12 + r] * co[s_ * 12 + c];
  }
}

extern "C" void kernel_launch(void* const* d_in, const int* in_sizes, int n_in,
                              void* d_out, int out_size, void* d_ws, size_t ws_size,
                              hipStream_t stream) {
  const float* board = (const float*)d_in[0];
  const float* card  = (const float*)d_in[1];
  const float* c1w = (const float*)d_in[2];
  const float* c1b = (const float*)d_in[3];
  const float* c2w = (const float*)d_in[4];
  const float* c2b = (const float*)d_in[5];
  const float* f1w = (const float*)d_in[6];
  const float* f1b = (const float*)d_in[7];
  const float* f2w = (const float*)d_in[8];
  const float* f2b = (const float*)d_in[9];
  const float* r1w = (const float*)d_in[10];
  const float* r1b = (const float*)d_in[11];
  const float* r2w = (const float*)d_in[12];
  const float* r2b = (const float*)d_in[13];
  const float* r3w = (const float*)d_in[14];
  const float* r3b = (const float*)d_in[15];
  const float* co1w = (const float*)d_in[16];
  const float* co1b = (const float*)d_in[17];
  const float* co2w = (const float*)d_in[18];
  const float* co2b = (const float*)d_in[19];
  const float* co3w = (const float*)d_in[20];
  const float* co3b = (const float*)d_in[21];
  const float* h1w = (const float*)d_in[22];
  const float* h1b = (const float*)d_in[23];
  const float* h2w = (const float*)d_in[24];
  const float* h2b = (const float*)d_in[25];
  const float* h3w = (const float*)d_in[26];
  const float* h3b = (const float*)d_in[27];

  float* ws = (float*)d_ws;
  float* out = (float*)d_out;
  float* a1  = ws + OFF_A1;
  float* a2t = ws + OFF_A2;

  k_prep<<<32, 256, 0, stream>>>(f1w, f2w, r1w, r2w, r3w, co1w, co2w, co3w, h1w, h2w, h3w, ws);
  k_conv1<<<1024, 512, 0, stream>>>(board, c1w, c1b, a1);
  k_conv2<<<512, 512, 0, stream>>>(a1, c2w, c2b, a2t);
  k_fc<<<256, 512, 0, stream>>>(a2t, card, ws, f1b, f2b,
                                r1b, r2b, r3b, co1b, co2b, co3b, h1b, h2b, h3b, out);
}

// Round 6
// 430.837 us; speedup vs baseline: 2.1174x; 1.0060x over previous
//
#include <hip/hip_runtime.h>
#include <hip/hip_bf16.h>
#include <cstdint>

// ---------------- workspace layout (float offsets) ----------------
// a1 layout: [32 ic][9 q4][16384 s] of float4   (conv1 out, relu'd)
// a2 layout: [64 oc][16384 s] of float4         (pooled, transposed)
#define N_A1   (16384ull*1152ull)
#define N_A2   (16384ull*256ull)
#define OFF_A1   0ull
#define OFF_A2   (OFF_A1 + N_A1)
#define OFF_W1T  (OFF_A2 + N_A2)           // fc1_w^T  [256][128]
#define OFF_W2T  (OFF_W1T + 32768ull)      // fc2_w^T  [135][64]
#define OFF_R1T  (OFF_W2T + 8640ull)
#define OFF_R2T  (OFF_R1T + 2048ull)
#define OFF_R3T  (OFF_R2T + 512ull)
#define OFF_C1T  (OFF_R3T + 160ull)
#define OFF_C2T  (OFF_C1T + 2048ull)
#define OFF_C3T  (OFF_C2T + 512ull)
#define OFF_H1T  (OFF_C3T + 160ull)
#define OFF_H2T  (OFF_H1T + 2048ull)
#define OFF_H3T  (OFF_H2T + 512ull)

typedef __attribute__((address_space(1))) const unsigned int GU32;
typedef __attribute__((address_space(3))) unsigned int LU32;
__device__ __forceinline__ void gl_lds16(const void* g, void* l) {
  __builtin_amdgcn_global_load_lds((GU32*)g, (LU32*)l, 16, 0, 0);
}

// unaligned-capable vector types (dword-aligned global rows of 10 floats)
typedef float f4u __attribute__((vector_size(16), aligned(4)));
typedef float f2u __attribute__((vector_size(8), aligned(4)));

#define COMPF(v, j) ((j)==0 ? (v).x : (j)==1 ? (v).y : (j)==2 ? (v).z : (v).w)

// ---------------- prep: transpose all FC/head weights ----------------
__global__ __launch_bounds__(256) void k_prep(
    const float* __restrict__ f1w, const float* __restrict__ f2w,
    const float* __restrict__ r1, const float* __restrict__ r2, const float* __restrict__ r3,
    const float* __restrict__ c1, const float* __restrict__ c2, const float* __restrict__ c3,
    const float* __restrict__ h1, const float* __restrict__ h2, const float* __restrict__ h3,
    float* __restrict__ ws) {
  const float* srcs[11] = {f1w, f2w, r1, r2, r3, c1, c2, c3, h1, h2, h3};
  float* dsts[11] = {ws+OFF_W1T, ws+OFF_W2T, ws+OFF_R1T, ws+OFF_R2T, ws+OFF_R3T,
                     ws+OFF_C1T, ws+OFF_C2T, ws+OFF_C3T, ws+OFF_H1T, ws+OFF_H2T, ws+OFF_H3T};
  const int Rs[11] = {128, 64, 32, 16, 10, 32, 16, 10, 32, 16, 7};
  const int Cs[11] = {256, 135, 64, 32, 16, 64, 32, 16, 64, 32, 16};
  for (int seg = 0; seg < 11; ++seg) {
    int n = Rs[seg] * Cs[seg];
    for (int i = blockIdx.x * blockDim.x + threadIdx.x; i < n; i += gridDim.x * blockDim.x) {
      int r = i / Cs[seg];
      int c = i - r * Cs[seg];
      dsts[seg][c * Rs[seg] + r] = srcs[seg][i];
    }
  }
}

// ---------------- conv1: board[B,9,10,10] -> relu -> a1[oc][q4][s] ----------------
// 512 thr = 8 waves; wave = 32 samples x 2 row-halves; thread = 3 out rows x 2 oc.
// block = 16 oc, tile = 32 samples; 2 blocks/tile; grid 1024 (XCD-colocated pairs).
// ~95 VGPR by design: acc 36 + window 36 + stage 10 + addr.
__global__ __launch_bounds__(512) void k_conv1(
    const float* __restrict__ board, const float* __restrict__ w,
    const float* __restrict__ bias_g, float* __restrict__ a1) {
  __shared__ float4 buf[2][960];              // [row 10][f 3][s 32], 30.7 KB
  const int tid  = threadIdx.x;
  const int lane = tid & 63;
  const int s    = lane & 31;                 // sample within tile
  const int hf   = lane >> 5;                 // row-half: 0 -> rows 0-2, 1 -> rows 3-5
  const int wv   = __builtin_amdgcn_readfirstlane(tid >> 6);

  const int bid  = blockIdx.x;
  const int xcd  = bid & 7;
  const int q    = bid >> 3;                  // 0..127
  const int ocb  = (q & 1) * 16;
  const int tile = (q >> 1) * 8 + xcd;        // 0..511; same-tile pair shares XCD
  const int s0   = tile * 32;
  const int oc0  = ocb + wv * 2;              // wave-uniform oc pair

  // staging role: threads 0..319 stage one (sample, row) each
  const int srow = tid >> 5;                  // 0..15, active < 10
  const int ss   = tid & 31;
  const bool stg = srow < 10;
  const float* gb = board + (size_t)(s0 + ss) * 900 + srow * 10;

  f4u sa, sb; f2u sc;
  if (stg) {
    sa = *(const f4u*)(gb + 0);
    sb = *(const f4u*)(gb + 4);
    sc = *(const f2u*)(gb + 8);
    *(f4u*)&buf[0][(srow*3 + 0)*32 + ss] = sa;
    *(f4u*)&buf[0][(srow*3 + 1)*32 + ss] = sb;
    *(f2u*)&buf[0][(srow*3 + 2)*32 + ss] = sc;
  }
  __syncthreads();

  float acc[2][18];
#pragma unroll
  for (int o = 0; o < 2; ++o) {
    const float bv = bias_g[oc0 + o];
#pragma unroll
    for (int p = 0; p < 18; ++p) acc[o][p] = bv;
  }

  // per-lane LDS base in float4 units; all reads are base + compile-time offset
  const int lbase = hf * (3 * 3 * 32) + s;

  float4 rwq[3][3];                           // sliding 3-row window (slot = row % 3)
#pragma unroll 1
  for (int ic = 0; ic < 9; ++ic) {
    const int cur = ic & 1;
    if (ic < 8 && stg) {                      // prefetch next ic to regs (T14)
      const float* g = gb + (ic + 1) * 100;
      sa = *(const f4u*)(g);
      sb = *(const f4u*)(g + 4);
      sc = *(const f2u*)(g + 8);
    }
    const float* wA = w + (size_t)oc0 * 225 + ic * 25;   // uniform -> s_load
    const float* wB = wA + 225;

#pragma unroll
    for (int ky = 0; ky < 5; ++ky) {
      if (ky == 0) {
#pragma unroll
        for (int rl = 0; rl < 3; ++rl)
#pragma unroll
          for (int f = 0; f < 3; ++f)
            rwq[rl][f] = buf[cur][lbase + (rl * 3 + f) * 32];
      } else {
#pragma unroll
        for (int f = 0; f < 3; ++f)
          rwq[(ky + 2) % 3][f] = buf[cur][lbase + ((ky + 2) * 3 + f) * 32];
      }
#pragma unroll
      for (int kx = 0; kx < 5; ++kx) {
        const float wa = wA[ky * 5 + kx];
        const float wb = wB[ky * 5 + kx];
#pragma unroll
        for (int r = 0; r < 3; ++r) {
#pragma unroll
          for (int c2 = 0; c2 < 6; ++c2) {
            const int d = c2 + kx;                       // 0..9, compile-time
            const float4 vv = rwq[(ky + r) % 3][d >> 2];
            const float xv = COMPF(vv, d & 3);
            acc[0][r*6 + c2] = fmaf(wa, xv, acc[0][r*6 + c2]);
            acc[1][r*6 + c2] = fmaf(wb, xv, acc[1][r*6 + c2]);
          }
        }
      }
    }
    if (ic < 8) {
      __syncthreads();                        // everyone done reading buf[cur^1] (at ic-1)
      if (stg) {
        *(f4u*)&buf[cur^1][(srow*3 + 0)*32 + ss] = sa;
        *(f4u*)&buf[cur^1][(srow*3 + 1)*32 + ss] = sb;
        *(f2u*)&buf[cur^1][(srow*3 + 2)*32 + ss] = sc;
      }
      __syncthreads();
    }
  }

  // relu + store. Thread owns out rows hf*3..hf*3+2 (p = hf*18 + local).
  // f4 stores at q4 = hf*5 + qq use local = 4qq + j + 2*hf; split f4 (q4=4) as f2.
  float4* o4 = reinterpret_cast<float4*>(a1);
#pragma unroll
  for (int o = 0; o < 2; ++o) {
    const int oc = oc0 + o;
#pragma unroll
    for (int qq = 0; qq < 4; ++qq) {
      float4 v;
      v.x = fmaxf(hf ? acc[o][4*qq + 2] : acc[o][4*qq + 0], 0.f);
      v.y = fmaxf(hf ? acc[o][4*qq + 3] : acc[o][4*qq + 1], 0.f);
      v.z = fmaxf(hf ? acc[o][4*qq + 4] : acc[o][4*qq + 2], 0.f);
      v.w = fmaxf(hf ? acc[o][4*qq + 5] : acc[o][4*qq + 3], 0.f);
      o4[(size_t)(oc * 9 + hf * 5 + qq) * 16384ull + s0 + s] = v;
    }
    float2 h2;
    h2.x = fmaxf(hf ? acc[o][0] : acc[o][16], 0.f);
    h2.y = fmaxf(hf ? acc[o][1] : acc[o][17], 0.f);
    float2* o2 = reinterpret_cast<float2*>(&o4[(size_t)(oc * 9 + 4) * 16384ull + s0 + s]);
    o2[hf] = h2;
  }
}

// -------- conv2 + relu + 2x2 maxpool: a1 -> a2T[oc][s] --------
// 512 thr = 8 waves; lane = sample (64/tile); wave = 4 oc; block = 32 oc.
// grid = 256 tiles * 2 ocb = 512 (XCD-colocated pairs).
__global__ __launch_bounds__(512) void k_conv2(
    const float* __restrict__ a1, const float* __restrict__ w,
    const float* __restrict__ bias_g, float* __restrict__ a2t) {
  __shared__ float4 buf[2][2304];             // [icl 4][q4 9][s 64] per chunk, 73.7 KB
  const int tid = threadIdx.x;
  const int s   = tid & 63;
  const int wv  = __builtin_amdgcn_readfirstlane(tid >> 6);
  const int bid = blockIdx.x;
  const int xcd = bid & 7;
  const int q   = bid >> 3;                   // 0..63
  const int ocb = (q & 1) * 32 + wv * 4;      // wave's 4-oc base (uniform)
  const int s0  = ((q >> 1) * 8 + xcd) * 64;  // tile 0..255, pair shares XCD

  const float4* a14 = reinterpret_cast<const float4*>(a1);

#define C2_STAGE(c_, b_)                                                      \
  {                                                                           \
    _Pragma("unroll")                                                         \
    for (int r = 0; r < 4; ++r) {                                             \
      int sg = wv + 8 * r;                                                    \
      gl_lds16(&a14[(size_t)((c_) * 36 + sg) * 16384ull + s0 + s],           \
               &buf[b_][sg * 64]);                                            \
    }                                                                         \
    if (wv < 4)                                                               \
      gl_lds16(&a14[(size_t)((c_) * 36 + 32 + wv) * 16384ull + s0 + s],      \
               &buf[b_][(32 + wv) * 64]);                                     \
  }

  C2_STAGE(0, 0);
  __syncthreads();

  float acc[4][16];
#pragma unroll
  for (int j = 0; j < 4; ++j) {
    float bv = bias_g[ocb + j];
#pragma unroll
    for (int p = 0; p < 16; ++p) acc[j][p] = bv;
  }

#pragma unroll 1
  for (int c = 0; c < 8; ++c) {
    const int cur = c & 1;
    if (c < 7) C2_STAGE(c + 1, cur ^ 1);

    for (int icl = 0; icl < 4; ++icl) {
      float plane[36];
#pragma unroll
      for (int q4 = 0; q4 < 9; ++q4) {
        float4 v = buf[cur][(icl * 9 + q4) * 64 + s];
        plane[q4*4] = v.x; plane[q4*4+1] = v.y; plane[q4*4+2] = v.z; plane[q4*4+3] = v.w;
      }
      const int ic = c * 4 + icl;
#pragma unroll
      for (int j = 0; j < 4; ++j) {
        const float* wr = w + (size_t)(ocb + j) * 288 + ic * 9;   // uniform -> s_load
#pragma unroll
        for (int ky = 0; ky < 3; ++ky) {
#pragma unroll
          for (int kx = 0; kx < 3; ++kx) {
            const float wt = wr[ky * 3 + kx];
#pragma unroll
            for (int y = 0; y < 4; ++y) {
#pragma unroll
              for (int x = 0; x < 4; ++x) {
                acc[j][y*4+x] = fmaf(wt, plane[(y+ky)*6 + x + kx], acc[j][y*4+x]);
              }
            }
          }
        }
      }
    }
    __syncthreads();
  }

  // pool + relu -> a2T[oc][s]: coalesced f4 store per oc
  float4* o4 = reinterpret_cast<float4*>(a2t);
#pragma unroll
  for (int j = 0; j < 4; ++j) {
    float4 v;
    v.x = fmaxf(fmaxf(acc[j][0],  acc[j][1]),  fmaxf(acc[j][4],  acc[j][5]));
    v.y = fmaxf(fmaxf(acc[j][2],  acc[j][3]),  fmaxf(acc[j][6],  acc[j][7]));
    v.z = fmaxf(fmaxf(acc[j][8],  acc[j][9]),  fmaxf(acc[j][12], acc[j][13]));
    v.w = fmaxf(fmaxf(acc[j][10], acc[j][11]), fmaxf(acc[j][14], acc[j][15]));
    v.x = fmaxf(v.x, 0.f); v.y = fmaxf(v.y, 0.f); v.z = fmaxf(v.z, 0.f); v.w = fmaxf(v.w, 0.f);
    o4[(size_t)(ocb + j) * 16384ull + s0 + s] = v;
  }
#undef C2_STAGE
}

// -------- fc1 -> concat -> fc2 -> 3 heads -> outer product --------
// 512 thr = 8 waves; lane = sample (64/block); grid 256.
__global__ __launch_bounds__(512) void k_fc(
    const float* __restrict__ a2t, const float* __restrict__ card,
    const float* __restrict__ ws,
    const float* __restrict__ f1b, const float* __restrict__ f2b,
    const float* __restrict__ rb1, const float* __restrict__ rb2, const float* __restrict__ rb3,
    const float* __restrict__ cb1, const float* __restrict__ cb2, const float* __restrict__ cb3,
    const float* __restrict__ hb1g, const float* __restrict__ hb2g, const float* __restrict__ hb3g,
    float* __restrict__ out) {
  __shared__ float xb[64 * 257];
  __shared__ float cbuf[64 * 8];
  __shared__ float h1s[64 * 129];
  __shared__ float h2s[64 * 65];
  __shared__ float ro[64 * 12];
  __shared__ float co[64 * 12];
  __shared__ float ha[64 * 8];
  const int tid = threadIdx.x;
  const int s0 = blockIdx.x * 64;
  const float4* x4 = reinterpret_cast<const float4*>(a2t);

  for (int i = tid; i < 4096; i += 512) {
    int k4 = i >> 6, s_ = i & 63;
    float4 v = x4[(size_t)k4 * 16384ull + s0 + s_];
    float* dst = &xb[s_ * 257 + k4 * 4];
    dst[0] = v.x; dst[1] = v.y; dst[2] = v.z; dst[3] = v.w;
  }
  if (tid < 448) {
    int s_ = tid / 7, k_ = tid - s_ * 7;
    cbuf[s_ * 8 + k_] = card[(size_t)(s0 + s_) * 7ull + k_];
  }
  __syncthreads();

  const int s = tid & 63;
  const int grp = __builtin_amdgcn_readfirstlane(tid >> 6);
  const float* w1t = ws + OFF_W1T;
  const float* w2t = ws + OFF_W2T;

  {
    const int j0 = grp * 16;
    float acc[16];
#pragma unroll
    for (int j = 0; j < 16; ++j) acc[j] = f1b[j0 + j];
    for (int k = 0; k < 256; ++k) {
      float xk = xb[s * 257 + k];
      const float* wr = w1t + k * 128 + j0;
#pragma unroll
      for (int j = 0; j < 16; ++j) acc[j] = fmaf(xk, wr[j], acc[j]);
    }
#pragma unroll
    for (int j = 0; j < 16; ++j) h1s[s * 129 + j0 + j] = fmaxf(acc[j], 0.f);
  }
  __syncthreads();

  {
    const int m0 = grp * 8;
    float acc[8];
#pragma unroll
    for (int m = 0; m < 8; ++m) acc[m] = f2b[m0 + m];
    for (int k = 0; k < 128; ++k) {
      float hk = h1s[s * 129 + k];
      const float* wr = w2t + k * 64 + m0;
#pragma unroll
      for (int m = 0; m < 8; ++m) acc[m] = fmaf(hk, wr[m], acc[m]);
    }
#pragma unroll
    for (int k = 0; k < 7; ++k) {
      float hk = cbuf[s * 8 + k];
      const float* wr = w2t + (128 + k) * 64 + m0;
#pragma unroll
      for (int m = 0; m < 8; ++m) acc[m] = fmaf(hk, wr[m], acc[m]);
    }
#pragma unroll
    for (int m = 0; m < 8; ++m) h2s[s * 65 + m0 + m] = fmaxf(acc[m], 0.f);
  }
  __syncthreads();

  if (grp < 3) {
    const float* hw1 = (grp == 0) ? ws + OFF_R1T : (grp == 1) ? ws + OFF_C1T : ws + OFF_H1T;
    const float* hw2 = (grp == 0) ? ws + OFF_R2T : (grp == 1) ? ws + OFF_C2T : ws + OFF_H2T;
    const float* hw3 = (grp == 0) ? ws + OFF_R3T : (grp == 1) ? ws + OFF_C3T : ws + OFF_H3T;
    const float* b1 = (grp == 0) ? rb1 : (grp == 1) ? cb1 : hb1g;
    const float* b2 = (grp == 0) ? rb2 : (grp == 1) ? cb2 : hb2g;
    const float* b3 = (grp == 0) ? rb3 : (grp == 1) ? cb3 : hb3g;

    float g1[32];
#pragma unroll
    for (int j = 0; j < 32; ++j) g1[j] = b1[j];
    for (int k = 0; k < 64; ++k) {
      float hk = h2s[s * 65 + k];
      const float* wr = hw1 + k * 32;
#pragma unroll
      for (int j = 0; j < 32; ++j) g1[j] = fmaf(hk, wr[j], g1[j]);
    }
    float g2[16];
#pragma unroll
    for (int m = 0; m < 16; ++m) g2[m] = b2[m];
#pragma unroll
    for (int k = 0; k < 32; ++k) {
      const float* wr = hw2 + k * 16;
#pragma unroll
      for (int m = 0; m < 16; ++m) g2[m] = fmaf(g1[k], wr[m], g2[m]);
    }
    if (grp == 2) {
      float g3[7];
#pragma unroll
      for (int m = 0; m < 7; ++m) g3[m] = b3[m];
#pragma unroll
      for (int k = 0; k < 16; ++k) {
        const float* wr = hw3 + k * 7;
#pragma unroll
        for (int m = 0; m < 7; ++m) g3[m] = fmaf(g2[k], wr[m], g3[m]);
      }
#pragma unroll
      for (int m = 0; m < 7; ++m) ha[s * 8 + m] = g3[m];
    } else {
      float g3[10];
#pragma unroll
      for (int m = 0; m < 10; ++m) g3[m] = b3[m];
#pragma unroll
      for (int k = 0; k < 16; ++k) {
        const float* wr = hw3 + k * 10;
#pragma unroll
        for (int m = 0; m < 10; ++m) g3[m] = fmaf(g2[k], wr[m], g3[m]);
      }
      float* dst = (grp == 0) ? ro : co;
#pragma unroll
      for (int m = 0; m < 10; ++m) dst[s * 12 + m] = g3[m];
    }
  }
  __syncthreads();

  for (int idx = tid; idx < 64 * 700; idx += 512) {
    int s_ = idx / 700;
    int q = idx - s_ * 700;
    int h = q / 100;
    int rm = q - h * 100;
    int r = rm / 10;
    int c = rm - r * 10;
    out[(size_t)(s0 + s_) * 700ull + q] = ha[s_ * 8 + h] * ro[s_ * 12 + r] * co[s_ * 12 + c];
  }
}

extern "C" void kernel_launch(void* const* d_in, const int* in_sizes, int n_in,
                              void* d_out, int out_size, void* d_ws, size_t ws_size,
                              hipStream_t stream) {
  const float* board = (const float*)d_in[0];
  const float* card  = (const float*)d_in[1];
  const float* c1w = (const float*)d_in[2];
  const float* c1b = (const float*)d_in[3];
  const float* c2w = (const float*)d_in[4];
  const float* c2b = (const float*)d_in[5];
  const float* f1w = (const float*)d_in[6];
  const float* f1b = (const float*)d_in[7];
  const float* f2w = (const float*)d_in[8];
  const float* f2b = (const float*)d_in[9];
  const float* r1w = (const float*)d_in[10];
  const float* r1b = (const float*)d_in[11];
  const float* r2w = (const float*)d_in[12];
  const float* r2b = (const float*)d_in[13];
  const float* r3w = (const float*)d_in[14];
  const float* r3b = (const float*)d_in[15];
  const float* co1w = (const float*)d_in[16];
  const float* co1b = (const float*)d_in[17];
  const float* co2w = (const float*)d_in[18];
  const float* co2b = (const float*)d_in[19];
  const float* co3w = (const float*)d_in[20];
  const float* co3b = (const float*)d_in[21];
  const float* h1w = (const float*)d_in[22];
  const float* h1b = (const float*)d_in[23];
  const float* h2w = (const float*)d_in[24];
  const float* h2b = (const float*)d_in[25];
  const float* h3w = (const float*)d_in[26];
  const float* h3b = (const float*)d_in[27];

  float* ws = (float*)d_ws;
  float* out = (float*)d_out;
  float* a1  = ws + OFF_A1;
  float* a2t = ws + OFF_A2;

  k_prep<<<32, 256, 0, stream>>>(f1w, f2w, r1w, r2w, r3w, co1w, co2w, co3w, h1w, h2w, h3w, ws);
  k_conv1<<<1024, 512, 0, stream>>>(board, c1w, c1b, a1);
  k_conv2<<<512, 512, 0, stream>>>(a1, c2w, c2b, a2t);
  k_fc<<<256, 512, 0, stream>>>(a2t, card, ws, f1b, f2b,
                                r1b, r2b, r3b, co1b, co2b, co3b, h1b, h2b, h3b, out);
}